// Round 3
// baseline (315.935 us; speedup 1.0000x reference)
//
#include <hip/hip_runtime.h>
#include <math.h>

#define NS 96
#define SM1 95
#define NC 32
#define REPS 1e-10f

// ---------------------------------------------------------------------------
// Kernel 1: per-ray alpha + transmittance scan + weights.
// One WAVE (64 lanes) per ray, 4 rays per 256-thread block.
// Shuffle-only scan: zero barriers, zero LDS.
// Lane L owns samples i0=L (always) and i1=64+L (when in range).
// ---------------------------------------------------------------------------
__global__ __launch_bounds__(256) void raymarch_scan(
    const float* __restrict__ densities,  // [rays, 96]
    const float* __restrict__ depths,     // [rays, 96]
    float* __restrict__ out_depth,        // [rays] (unclipped, nan->inf)
    float* __restrict__ out_w,            // [rays, 95]
    float* __restrict__ out_alpha,        // [rays, 95]
    float* __restrict__ out_wbg,          // [rays]
    float* __restrict__ ws_coeff,         // [rays, 96]
    float* __restrict__ ws_d0,            // [rays]
    float* __restrict__ ws_d1)            // [rays]
{
    const int ray  = blockIdx.x * 4 + (threadIdx.x >> 6);
    const int lane = threadIdx.x & 63;

    const float* dep = depths + (size_t)ray * NS;
    const float* den = densities + (size_t)ray * NS;

    const int i1 = 64 + lane;
    float dep0 = dep[lane];
    float den0 = den[lane];
    float dep1 = (i1 < NS) ? dep[i1] : 0.0f;
    float den1 = (i1 < NS) ? den[i1] : 0.0f;

    // neighbor (i+1) values via shuffle
    float dn0 = __shfl(dep0, (lane + 1) & 63);
    float en0 = __shfl(den0, (lane + 1) & 63);
    float d64 = __shfl(dep1, 0);
    float e64 = __shfl(den1, 0);
    if (lane == 63) { dn0 = d64; en0 = e64; }
    float dn1 = __shfl(dep1, (lane + 1) & 63);  // valid for lane < 31
    float en1 = __shfl(den1, (lane + 1) & 63);

    // alpha for sample i0 = lane (all 64 lanes valid: lane <= 63 < 95)
    float dm0  = 0.5f * (den0 + en0) - 1.0f;
    float sp0  = fmaxf(dm0, 0.0f) + __logf(1.0f + __expf(-fabsf(dm0)));
    float a0   = 1.0f - __expf(-sp0 * (dn0 - dep0));
    float mid0 = 0.5f * (dep0 + dn0);

    // alpha for sample i1 = 64+lane (valid for lane < 31)
    float a1 = 0.0f, mid1 = 0.0f;
    if (lane < 31) {
        float dm1 = 0.5f * (den1 + en1) - 1.0f;
        float sp1 = fmaxf(dm1, 0.0f) + __logf(1.0f + __expf(-fabsf(dm1)));
        a1   = 1.0f - __expf(-sp1 * (dn1 - dep1));
        mid1 = 0.5f * (dep1 + dn1);
    }

    float oma0 = 1.0f - a0 + REPS;
    float oma1 = (lane < 31) ? (1.0f - a1 + REPS) : 1.0f;

    // inclusive multiplicative scan of oma0 over lanes 0..63
    float x = oma0;
    #pragma unroll
    for (int off = 1; off < 64; off <<= 1) {
        float v = __shfl_up(x, off);
        if (lane >= off) x *= v;
    }
    float total0 = __shfl(x, 63);  // prod oma[0..63]

    // inclusive scan of oma1 (identity-padded past lane 30)
    float y = oma1;
    #pragma unroll
    for (int off = 1; off < 64; off <<= 1) {
        float v = __shfl_up(y, off);
        if (lane >= off) y *= v;
    }

    // transmittance before each sample; weights
    float xs = __shfl_up(x, 1);
    float T0 = (lane == 0) ? 1.0f : xs;
    float w0 = a0 * T0;
    float ys = __shfl_up(y, 1);
    float T1 = ((lane == 0) ? 1.0f : ys) * total0;
    float w1 = a1 * T1;  // a1 == 0 for lane >= 31

    float wbg = __shfl(y, 30) * total0;  // prod oma[0..94]

    // coeff[s] = 0.5*(w[s-1] + w[s]), w[-1] = w[95] = 0
    float w0p = __shfl_up(w0, 1);
    float c0  = 0.5f * (((lane == 0) ? 0.0f : w0p) + w0);
    float w1p = __shfl_up(w1, 1);
    float w63 = __shfl(w0, 63);
    float c1  = 0.5f * (((lane == 0) ? w63 : w1p) + w1);  // s = 64+lane

    // wsum / dsum butterfly reduction
    float wsum = w0 + w1;
    float dsum = w0 * mid0 + ((lane < 31) ? w1 * mid1 : 0.0f);
    #pragma unroll
    for (int off = 32; off > 0; off >>= 1) {
        wsum += __shfl_xor(wsum, off);
        dsum += __shfl_xor(dsum, off);
    }

    // stores (lane-contiguous, coalesced)
    const size_t b95 = (size_t)ray * SM1;
    const size_t b96 = (size_t)ray * NS;
    out_alpha[b95 + lane] = a0;
    out_w[b95 + lane]     = w0;
    ws_coeff[b96 + lane]  = c0;
    if (lane < 31) {
        out_alpha[b95 + 64 + lane] = a1;
        out_w[b95 + 64 + lane]     = w1;
    }
    if (lane < 32) {
        ws_coeff[b96 + 64 + lane] = c1;
    }
    float dlast = __shfl(dep1, 31);  // dep[95]
    if (lane == 0) {
        out_wbg[ray] = wbg;
        float cd = dsum / wsum;
        if (cd != cd) cd = __builtin_inff();  // NaN -> inf; clip in finalize
        out_depth[ray] = cd;
        ws_d0[ray] = dep0;    // dep[0] (sorted along S)
        ws_d1[ray] = dlast;
    }
}

// ---------------------------------------------------------------------------
// Kernel 2: streaming color composite. 16 rays per 256-thread block.
// Thread t -> ray r = t>>4, half h = (t>>3)&1, channel-group g = t&7.
// Each thread accumulates float4 over its 48 samples; no barrier in loop.
// ---------------------------------------------------------------------------
__global__ __launch_bounds__(256) void raymarch_color(
    const float* __restrict__ colors,     // [rays, 96, 32]
    const float* __restrict__ ws_coeff,   // [rays, 96]
    float* __restrict__ out_rgb)          // [rays, 32]
{
    const int t  = threadIdx.x;
    const int r0 = blockIdx.x * 16;

    // coeff staged in LDS, padded stride 97 -> conflict-free broadcast reads
    __shared__ float s_coeff[16 * 97];

    #pragma unroll
    for (int k = 0; k < 6; ++k) {
        int i = t + k * 256;  // i in [0, 1536)
        int r = i / NS, s = i - r * NS;
        s_coeff[r * 97 + s] = ws_coeff[(size_t)(r0 + r) * NS + s];
    }
    __syncthreads();

    const int g = t & 7;
    const int h = (t >> 3) & 1;
    const int rl = t >> 4;
    const int ray = r0 + rl;
    const int sbase = h * 48;

    const float4* col4 = (const float4*)(colors + (size_t)ray * NS * NC);
    const float* cf = &s_coeff[rl * 97 + sbase];

    float4 acc = {0.0f, 0.0f, 0.0f, 0.0f};
    #pragma unroll 12
    for (int i = 0; i < 48; ++i) {
        float4 v = col4[(sbase + i) * 8 + g];
        float c = cf[i];
        acc.x = fmaf(c, v.x, acc.x);
        acc.y = fmaf(c, v.y, acc.y);
        acc.z = fmaf(c, v.z, acc.z);
        acc.w = fmaf(c, v.w, acc.w);
    }

    // merge the two sample-halves (partner is lane ^ 8 within the wave)
    acc.x += __shfl_xor(acc.x, 8);
    acc.y += __shfl_xor(acc.y, 8);
    acc.z += __shfl_xor(acc.z, 8);
    acc.w += __shfl_xor(acc.w, 8);

    if (h == 0) {
        float4 o;
        o.x = 2.0f * acc.x - 1.0f;
        o.y = 2.0f * acc.y - 1.0f;
        o.z = 2.0f * acc.z - 1.0f;
        o.w = 2.0f * acc.w - 1.0f;
        ((float4*)(out_rgb + (size_t)ray * NC))[g] = o;
    }
}

// ---------------------------------------------------------------------------
// Kernel 3: grid-wide min/max of depths (sorted along S -> endpoints), clip.
// ---------------------------------------------------------------------------
__global__ __launch_bounds__(256) void raymarch_finalize(
    const float* __restrict__ ws_d0,
    const float* __restrict__ ws_d1,
    float* __restrict__ out_depth,
    int rays)
{
    __shared__ float s_mn[256];
    __shared__ float s_mx[256];
    const int tid = threadIdx.x;

    float mn = __builtin_inff();
    float mx = -__builtin_inff();
    for (int r = tid; r < rays; r += 256) {
        mn = fminf(mn, ws_d0[r]);
        mx = fmaxf(mx, ws_d1[r]);
    }
    s_mn[tid] = mn;
    s_mx[tid] = mx;
    __syncthreads();
    for (int off = 128; off > 0; off >>= 1) {
        if (tid < off) {
            s_mn[tid] = fminf(s_mn[tid], s_mn[tid + off]);
            s_mx[tid] = fmaxf(s_mx[tid], s_mx[tid + off]);
        }
        __syncthreads();
    }
    const float dmin = s_mn[0];
    const float dmax = s_mx[0];

    const int r = blockIdx.x * 256 + tid;
    if (r < rays) {
        float cd = out_depth[r];
        cd = fminf(fmaxf(cd, dmin), dmax);  // clip(inf) -> dmax, matches jnp
        out_depth[r] = cd;
    }
}

extern "C" void kernel_launch(void* const* d_in, const int* in_sizes, int n_in,
                              void* d_out, int out_size, void* d_ws, size_t ws_size,
                              hipStream_t stream) {
    const float* colors    = (const float*)d_in[0];
    const float* densities = (const float*)d_in[1];
    const float* depths    = (const float*)d_in[2];

    const int rays = in_sizes[2] / NS;  // B*R = 16384

    float* out = (float*)d_out;
    float* out_rgb   = out;                                   // rays*32
    float* out_depth = out_rgb + (size_t)rays * NC;           // rays
    float* out_w     = out_depth + rays;                      // rays*95
    float* out_alpha = out_w + (size_t)rays * SM1;            // rays*95
    float* out_wbg   = out_alpha + (size_t)rays * SM1;        // rays

    float* ws       = (float*)d_ws;
    float* ws_d0    = ws;                                     // rays
    float* ws_d1    = ws + rays;                              // rays
    float* ws_coeff = ws + 2 * (size_t)rays;                  // rays*96

    raymarch_scan<<<rays / 4, 256, 0, stream>>>(
        densities, depths,
        out_depth, out_w, out_alpha, out_wbg, ws_coeff, ws_d0, ws_d1);

    raymarch_color<<<rays / 16, 256, 0, stream>>>(colors, ws_coeff, out_rgb);

    raymarch_finalize<<<(rays + 255) / 256, 256, 0, stream>>>(
        ws_d0, ws_d1, out_depth, rays);
}

// Round 4
// 302.450 us; speedup vs baseline: 1.0446x; 1.0446x over previous
//
#include <hip/hip_runtime.h>
#include <math.h>

#define NS 96
#define SM1 95
#define NC 32
#define REPS 1e-10f

// ---------------------------------------------------------------------------
// Fused kernel: one WAVE per ray (4 rays per 256-thread block).
//   Phase A (scan): shuffle-only transmittance scan -> w, alpha, wbg, depth,
//                   coeff kept in registers (c0: s=lane, c1: s=64+lane).
//   Phase B (color): lane = srow*8 + g; sample s = srow + 8k, k=0..11;
//                   float4 index = lane + 64k -> contiguous 1 KiB wave reads.
//                   coeff[s] fetched from scan registers via __shfl.
// Zero LDS, zero __syncthreads. Color loads issued first to overlap the scan.
// ---------------------------------------------------------------------------
__global__ __launch_bounds__(256) void raymarch_fused(
    const float* __restrict__ colors,     // [rays, 96, 32]
    const float* __restrict__ densities,  // [rays, 96]
    const float* __restrict__ depths,     // [rays, 96]
    float* __restrict__ out_rgb,          // [rays, 32]
    float* __restrict__ out_depth,        // [rays] (unclipped, nan->inf)
    float* __restrict__ out_w,            // [rays, 95]
    float* __restrict__ out_alpha,        // [rays, 95]
    float* __restrict__ out_wbg,          // [rays]
    float* __restrict__ ws_d0,            // [rays]
    float* __restrict__ ws_d1)            // [rays]
{
    const int ray  = blockIdx.x * 4 + (threadIdx.x >> 6);
    const int lane = threadIdx.x & 63;

    // ---- issue the heavy color loads first (12 x 1KiB coalesced waves) ----
    const float4* col4 = (const float4*)(colors + (size_t)ray * NS * NC);
    float4 v[12];
    #pragma unroll
    for (int k = 0; k < 12; ++k) {
        v[k] = col4[lane + 64 * k];
    }

    // ---- Phase A: scan (identical math to the verified R3 kernel) ----
    const float* dep = depths + (size_t)ray * NS;
    const float* den = densities + (size_t)ray * NS;

    const int i1 = 64 + lane;
    float dep0 = dep[lane];
    float den0 = den[lane];
    float dep1 = (i1 < NS) ? dep[i1] : 0.0f;
    float den1 = (i1 < NS) ? den[i1] : 0.0f;

    float dn0 = __shfl(dep0, (lane + 1) & 63);
    float en0 = __shfl(den0, (lane + 1) & 63);
    float d64 = __shfl(dep1, 0);
    float e64 = __shfl(den1, 0);
    if (lane == 63) { dn0 = d64; en0 = e64; }
    float dn1 = __shfl(dep1, (lane + 1) & 63);  // valid for lane < 31
    float en1 = __shfl(den1, (lane + 1) & 63);

    float dm0  = 0.5f * (den0 + en0) - 1.0f;
    float sp0  = fmaxf(dm0, 0.0f) + __logf(1.0f + __expf(-fabsf(dm0)));
    float a0   = 1.0f - __expf(-sp0 * (dn0 - dep0));
    float mid0 = 0.5f * (dep0 + dn0);

    float a1 = 0.0f, mid1 = 0.0f;
    if (lane < 31) {
        float dm1 = 0.5f * (den1 + en1) - 1.0f;
        float sp1 = fmaxf(dm1, 0.0f) + __logf(1.0f + __expf(-fabsf(dm1)));
        a1   = 1.0f - __expf(-sp1 * (dn1 - dep1));
        mid1 = 0.5f * (dep1 + dn1);
    }

    float oma0 = 1.0f - a0 + REPS;
    float oma1 = (lane < 31) ? (1.0f - a1 + REPS) : 1.0f;

    float x = oma0;
    #pragma unroll
    for (int off = 1; off < 64; off <<= 1) {
        float vv = __shfl_up(x, off);
        if (lane >= off) x *= vv;
    }
    float total0 = __shfl(x, 63);  // prod oma[0..63]

    float y = oma1;
    #pragma unroll
    for (int off = 1; off < 64; off <<= 1) {
        float vv = __shfl_up(y, off);
        if (lane >= off) y *= vv;
    }

    float xs = __shfl_up(x, 1);
    float T0 = (lane == 0) ? 1.0f : xs;
    float w0 = a0 * T0;
    float ys = __shfl_up(y, 1);
    float T1 = ((lane == 0) ? 1.0f : ys) * total0;
    float w1 = a1 * T1;  // a1 == 0 for lane >= 31

    float wbg = __shfl(y, 30) * total0;  // prod oma[0..94]

    // coeff[s] = 0.5*(w[s-1] + w[s]), with w[-1] = w[95] = 0
    float w0p = __shfl_up(w0, 1);
    float c0  = 0.5f * (((lane == 0) ? 0.0f : w0p) + w0);        // s = lane
    float w1p = __shfl_up(w1, 1);
    float w63 = __shfl(w0, 63);
    float c1  = 0.5f * (((lane == 0) ? w63 : w1p) + w1);         // s = 64+lane

    float wsum = w0 + w1;
    float dsum = w0 * mid0 + ((lane < 31) ? w1 * mid1 : 0.0f);
    #pragma unroll
    for (int off = 32; off > 0; off >>= 1) {
        wsum += __shfl_xor(wsum, off);
        dsum += __shfl_xor(dsum, off);
    }

    // scan-side stores (coalesced)
    const size_t b95 = (size_t)ray * SM1;
    out_alpha[b95 + lane] = a0;
    out_w[b95 + lane]     = w0;
    if (lane < 31) {
        out_alpha[b95 + 64 + lane] = a1;
        out_w[b95 + 64 + lane]     = w1;
    }
    float dlast = __shfl(dep1, 31);  // dep[95]
    if (lane == 0) {
        out_wbg[ray] = wbg;
        float cd = dsum / wsum;
        if (cd != cd) cd = __builtin_inff();  // NaN -> inf; clip in finalize
        out_depth[ray] = cd;
        ws_d0[ray] = dep0;   // dep[0] (depths sorted along S)
        ws_d1[ray] = dlast;
    }

    // ---- Phase B: color accumulate ----
    // lane = srow*8 + g; sample s = srow + 8k; coeff via shuffle from c0/c1.
    const int srow = lane >> 3;
    float4 acc = {0.0f, 0.0f, 0.0f, 0.0f};
    #pragma unroll
    for (int k = 0; k < 8; ++k) {
        float c = __shfl(c0, srow + 8 * k);          // s = srow + 8k < 64
        acc.x = fmaf(c, v[k].x, acc.x);
        acc.y = fmaf(c, v[k].y, acc.y);
        acc.z = fmaf(c, v[k].z, acc.z);
        acc.w = fmaf(c, v[k].w, acc.w);
    }
    #pragma unroll
    for (int k = 8; k < 12; ++k) {
        float c = __shfl(c1, srow + 8 * (k - 8));    // s = 64 + srow + 8(k-8)
        acc.x = fmaf(c, v[k].x, acc.x);
        acc.y = fmaf(c, v[k].y, acc.y);
        acc.z = fmaf(c, v[k].z, acc.z);
        acc.w = fmaf(c, v[k].w, acc.w);
    }

    // reduce across the 8 srow groups (partners differ only in srow bits)
    #pragma unroll
    for (int m = 8; m < 64; m <<= 1) {
        acc.x += __shfl_xor(acc.x, m);
        acc.y += __shfl_xor(acc.y, m);
        acc.z += __shfl_xor(acc.z, m);
        acc.w += __shfl_xor(acc.w, m);
    }

    if (lane < 8) {  // g = lane; 8 lanes store 128B contiguous per ray
        float4 o;
        o.x = 2.0f * acc.x - 1.0f;
        o.y = 2.0f * acc.y - 1.0f;
        o.z = 2.0f * acc.z - 1.0f;
        o.w = 2.0f * acc.w - 1.0f;
        ((float4*)(out_rgb + (size_t)ray * NC))[lane] = o;
    }
}

// ---------------------------------------------------------------------------
// Finalize: grid-wide min/max of depths (sorted along S -> endpoints), clip.
// ---------------------------------------------------------------------------
__global__ __launch_bounds__(256) void raymarch_finalize(
    const float* __restrict__ ws_d0,
    const float* __restrict__ ws_d1,
    float* __restrict__ out_depth,
    int rays)
{
    __shared__ float s_mn[256];
    __shared__ float s_mx[256];
    const int tid = threadIdx.x;

    float mn = __builtin_inff();
    float mx = -__builtin_inff();
    for (int r = tid; r < rays; r += 256) {
        mn = fminf(mn, ws_d0[r]);
        mx = fmaxf(mx, ws_d1[r]);
    }
    s_mn[tid] = mn;
    s_mx[tid] = mx;
    __syncthreads();
    for (int off = 128; off > 0; off >>= 1) {
        if (tid < off) {
            s_mn[tid] = fminf(s_mn[tid], s_mn[tid + off]);
            s_mx[tid] = fmaxf(s_mx[tid], s_mx[tid + off]);
        }
        __syncthreads();
    }
    const float dmin = s_mn[0];
    const float dmax = s_mx[0];

    const int r = blockIdx.x * 256 + tid;
    if (r < rays) {
        float cd = out_depth[r];
        cd = fminf(fmaxf(cd, dmin), dmax);  // clip(inf) -> dmax, matches jnp
        out_depth[r] = cd;
    }
}

extern "C" void kernel_launch(void* const* d_in, const int* in_sizes, int n_in,
                              void* d_out, int out_size, void* d_ws, size_t ws_size,
                              hipStream_t stream) {
    const float* colors    = (const float*)d_in[0];
    const float* densities = (const float*)d_in[1];
    const float* depths    = (const float*)d_in[2];

    const int rays = in_sizes[2] / NS;  // B*R = 16384

    float* out = (float*)d_out;
    float* out_rgb   = out;                                   // rays*32
    float* out_depth = out_rgb + (size_t)rays * NC;           // rays
    float* out_w     = out_depth + rays;                      // rays*95
    float* out_alpha = out_w + (size_t)rays * SM1;            // rays*95
    float* out_wbg   = out_alpha + (size_t)rays * SM1;        // rays

    float* ws    = (float*)d_ws;
    float* ws_d0 = ws;                                        // rays
    float* ws_d1 = ws + rays;                                 // rays

    raymarch_fused<<<rays / 4, 256, 0, stream>>>(
        colors, densities, depths,
        out_rgb, out_depth, out_w, out_alpha, out_wbg, ws_d0, ws_d1);

    raymarch_finalize<<<(rays + 255) / 256, 256, 0, stream>>>(
        ws_d0, ws_d1, out_depth, rays);
}